// Round 6
// baseline (77.187 us; speedup 1.0000x reference)
//
#include <hip/hip_runtime.h>
#include <hip/hip_bf16.h>

#define CIN  64
#define HH   128
#define WW   128
#define COUT 64
#define K2   9
#define HW   (HH * WW)

typedef __attribute__((ext_vector_type(8))) short bf16x8;
typedef __attribute__((ext_vector_type(4))) float f32x4;
typedef __attribute__((ext_vector_type(2))) float f32x2;
typedef __attribute__((ext_vector_type(4))) unsigned short u16x4;

__device__ __forceinline__ unsigned short f2bf(float f) {
    __hip_bfloat16 h = __float2bfloat16(f);
    return *reinterpret_cast<unsigned short*>(&h);
}
// unpack dword holding 2 bf16 (lo=ch j, hi=ch j+1) -> f32x2
__device__ __forceinline__ f32x2 up2(unsigned int d) {
    f32x2 r;
    r[0] = __uint_as_float(d << 16);
    r[1] = __uint_as_float(d & 0xffff0000u);
    return r;
}

// ---------------- prep: x fp32 NCHW -> bf16 slice-planes [b][s][y][x][8ch] ----------------
// plane s holds channels 8s..8s+7; granule (y,x) is 16B contiguous.
__launch_bounds__(256)
__global__ void xprep2_kernel(const float* __restrict__ x, unsigned short* __restrict__ xt) {
    const int idx = blockIdx.x * 256 + threadIdx.x;   // 2^20 total
    const int xw = idx & 127;
    const int y  = (idx >> 7) & 127;
    const int s  = (idx >> 14) & 7;
    const int b  = idx >> 17;
    const float* src = x + (((size_t)(b * CIN + s * 8) * HH) + y) * WW + xw;
    union { unsigned short us[8]; bf16x8 v; } u;
    #pragma unroll
    for (int j = 0; j < 8; ++j) u.us[j] = f2bf(src[(size_t)j * HW]);
    *(bf16x8*)(xt + ((((size_t)b * 8 + s) * HW) + y * WW + xw) * 8) = u.v;
}

// ---------------- prep: weight fp32 [o][c][k] -> bf16 MFMA-B-fragment order ----------------
// wtp[ ((k*2+ks)*4+nt)*64*8 + l*8 + j ] = W[o=nt*16+(l&15)][c=ks*32+(l>>4)*8+j][k]
__global__ void wprep_kernel(const float* __restrict__ w, unsigned short* __restrict__ wtp) {
    int idx = blockIdx.x * 256 + threadIdx.x;
    if (idx >= COUT * CIN * K2) return;
    int j  = idx & 7;
    int l  = (idx >> 3) & 63;
    int nt = (idx >> 9) & 3;
    int ks = (idx >> 11) & 1;
    int k  = idx >> 12;
    int o  = nt * 16 + (l & 15);
    int c  = ks * 32 + (l >> 4) * 8 + j;
    wtp[idx] = f2bf(w[(o * CIN + c) * K2 + k]);
}

// ---------------- main: direct-to-fragment gather, zero LDS, pipelined ----------------
__launch_bounds__(256, 4)
__global__ void dcn_kernel(const unsigned short* __restrict__ xt,
                           const float* __restrict__ off,
                           const unsigned short* __restrict__ wtp,
                           float* __restrict__ out) {
    const int tid = threadIdx.x;
    const int w   = tid >> 6;
    const int l   = tid & 63;

    int bid = blockIdx.x;
    bid = (bid & 7) * 256 + (bid >> 3);         // XCD swizzle: one batch per XCD
    const int b   = bid >> 8;
    const int t   = bid & 255;
    const int ty0 = (t >> 4) << 3;
    const int tx0 = (t & 15) << 3;

    const int g      = l >> 4;                  // k-slice quad (A-frag minor index)
    const int lane16 = l & 15;                  // pixel within wave (A-frag row)

    f32x4 acc[4] = {{0,0,0,0},{0,0,0,0},{0,0,0,0},{0,0,0,0}};

    const float* offb = off + (size_t)b * (2 * K2) * HW;
    const unsigned short* xb  = xt + (size_t)b * HW * 64;
    const unsigned short* xp0 = xb + (size_t)g * HW * 8;        // plane for ks=0 (ch 8g..)
    const unsigned short* xp1 = xb + (size_t)(g + 4) * HW * 8;  // plane for ks=1 (ch 32+8g..)

    // this lane's pixel (params AND fragment both belong to it)
    const int pixA = w * 16 + lane16;
    const int ypA  = ty0 + (pixA >> 3);
    const int xpA  = tx0 + (pixA & 7);
    const int offp = ypA * WW + xpA;

    // ---- pipeline state: all literal-indexed / named (spill-safe) ----
    f32x4 Pw[2];                 // bilinear corner weights per slot
    int   Pr0[2], Pr1[2];        // (yc*WW+xL)*8 short-offsets, rows y0/y1
    float oyv[2], oxv[2];        // prefetched raw offsets
    bf16x8 G00L, G00R, G01L, G01R;   // ks=0: (y0,L/R), (y1,L/R)
    bf16x8 G10L, G10R, G11L, G11R;   // ks=1
    bf16x8 bvv[2][4];
    bf16x8 af0, af1;

#define PARAMS(K, S) do {                                                     \
    const int kdy = (K) / 3 - 1, kdx = (K) % 3 - 1;                           \
    float py = oyv[S] + (float)(ypA + kdy);                                   \
    float px = oxv[S] + (float)(xpA + kdx);                                   \
    float fy = floorf(py), fx = floorf(px);                                   \
    float wy = py - fy, wxn = px - fx;                                        \
    int y0 = (int)fy, x0i = (int)fx;                                          \
    int yc0 = min(max(y0,     0), HH - 1);                                    \
    int yc1 = min(max(y0 + 1, 0), HH - 1);                                    \
    float ay0 = (y0 >= 0  && y0 <= HH - 1) ? (1.f - wy) : 0.f;                \
    float ay1 = (y0 >= -1 && y0 <= HH - 2) ? wy         : 0.f;                \
    int   xL  = min(max(x0i, 0), WW - 2);                                     \
    float bx0 = (x0i >= 0  && x0i <= WW - 1) ? (1.f - wxn) : 0.f;             \
    float bx1 = (x0i >= -1 && x0i <= WW - 2) ? wxn         : 0.f;             \
    bool  sw  = (x0i != xL);                                                  \
    float wxa = sw ? bx1 : bx0;                                               \
    float wxb = sw ? bx0 : bx1;                                               \
    Pw[S][0] = ay0 * wxa; Pw[S][1] = ay0 * wxb;                               \
    Pw[S][2] = ay1 * wxa; Pw[S][3] = ay1 * wxb;                               \
    Pr0[S] = (yc0 * WW + xL) * 8;                                             \
    Pr1[S] = (yc1 * WW + xL) * 8;                                             \
} while (0)

#define GATHER(S) do {                                                        \
    const unsigned short* r0p = xp0 + Pr0[S];                                 \
    const unsigned short* r1p = xp0 + Pr1[S];                                 \
    const unsigned short* r2p = xp1 + Pr0[S];                                 \
    const unsigned short* r3p = xp1 + Pr1[S];                                 \
    G00L = *(const bf16x8*)(r0p); G00R = *(const bf16x8*)(r0p + 8);           \
    G01L = *(const bf16x8*)(r1p); G01R = *(const bf16x8*)(r1p + 8);           \
    G10L = *(const bf16x8*)(r2p); G10R = *(const bf16x8*)(r2p + 8);           \
    G11L = *(const bf16x8*)(r3p); G11R = *(const bf16x8*)(r3p + 8);           \
} while (0)

#define IN1(S, GA, GB, GC, GD, AF) do {                                       \
    union { bf16x8 v; unsigned int d[4]; } ua, ub, uc, ud;                    \
    ua.v = GA; ub.v = GB; uc.v = GC; ud.v = GD;                               \
    union { unsigned short us[8]; bf16x8 v; } rr;                             \
    _Pragma("unroll")                                                         \
    for (int q = 0; q < 4; ++q) {                                             \
        f32x2 v = up2(ua.d[q]) * Pw[S][0] + up2(ub.d[q]) * Pw[S][1]           \
                + up2(uc.d[q]) * Pw[S][2] + up2(ud.d[q]) * Pw[S][3];          \
        rr.us[2*q]   = f2bf(v[0]);                                            \
        rr.us[2*q+1] = f2bf(v[1]);                                            \
    }                                                                         \
    AF = rr.v;                                                                \
} while (0)

#define INTERP(S) do {                                                        \
    IN1(S, G00L, G00R, G01L, G01R, af0);                                      \
    IN1(S, G10L, G10R, G11L, G11R, af1);                                      \
} while (0)

#define BVLOAD(K) do {                                                        \
    _Pragma("unroll")                                                         \
    for (int ks = 0; ks < 2; ++ks)                                            \
        _Pragma("unroll")                                                     \
        for (int nt = 0; nt < 4; ++nt)                                        \
            bvv[ks][nt] = *(const bf16x8*)(wtp + ((((K)*2 + ks)*4 + nt)*64 + l)*8); \
} while (0)

#define DOMFMA() do {                                                         \
    __builtin_amdgcn_s_setprio(1);                                            \
    _Pragma("unroll")                                                         \
    for (int nt = 0; nt < 4; ++nt)                                            \
        acc[nt] = __builtin_amdgcn_mfma_f32_16x16x32_bf16(af0, bvv[0][nt], acc[nt], 0, 0, 0); \
    _Pragma("unroll")                                                         \
    for (int nt = 0; nt < 4; ++nt)                                            \
        acc[nt] = __builtin_amdgcn_mfma_f32_16x16x32_bf16(af1, bvv[1][nt], acc[nt], 0, 0, 0); \
    __builtin_amdgcn_s_setprio(0);                                            \
} while (0)

// steady state: params(k+1) -> offsets(k+2) -> bv(k) -> interp(k) ->
// gather(k+1) [in flight across MFMA(k) + params(k+2)] -> MFMA(k)
#define STEP(K, CUR, NXT) do {                                                \
    PARAMS((K) + 1, NXT);                                                     \
    if ((K) + 2 < K2) {                                                       \
        oyv[CUR] = offb[(2 * ((K) + 2)    ) * HW + offp];                     \
        oxv[CUR] = offb[(2 * ((K) + 2) + 1) * HW + offp];                     \
    }                                                                         \
    BVLOAD(K);                                                                \
    INTERP(CUR);                                                              \
    GATHER(NXT);                                                              \
    DOMFMA();                                                                 \
} while (0)

    // -------- prologue --------
    oyv[0] = offb[offp];          oxv[0] = offb[HW + offp];
    oyv[1] = offb[2 * HW + offp]; oxv[1] = offb[3 * HW + offp];
    PARAMS(0, 0);
    GATHER(0);

    // -------- pipelined taps --------
    STEP(0, 0, 1); STEP(1, 1, 0); STEP(2, 0, 1); STEP(3, 1, 0);
    STEP(4, 0, 1); STEP(5, 1, 0); STEP(6, 0, 1); STEP(7, 1, 0);
    // tail: tap 8 (params slot 0, stage filled by STEP(7))
    BVLOAD(8);
    INTERP(0);
    DOMFMA();

#undef PARAMS
#undef GATHER
#undef IN1
#undef INTERP
#undef BVLOAD
#undef DOMFMA
#undef STEP

    // -------- epilogue: f32x4 stores (4 consecutive x per lane, 16B aligned) --------
    const int o_lane = l & 15;
    const int rq     = (l >> 4) * 4;
    #pragma unroll
    for (int nt = 0; nt < 4; ++nt) {
        const int o   = nt * 16 + o_lane;
        const int pix = w * 16 + rq;
        const int yy  = ty0 + (pix >> 3);
        const int xx  = tx0 + (pix & 7);
        *(f32x4*)&out[(((size_t)b * COUT + o) * HH + yy) * WW + xx] = acc[nt];
    }
}

// ---------------- fallback path (no xt room): R0 kernel ----------------
__global__ void wprep_fb(const float* __restrict__ w, unsigned short* __restrict__ wt) {
    int idx = blockIdx.x * 256 + threadIdx.x;
    if (idx >= COUT * CIN * K2) return;
    int o = idx / (CIN * K2);
    int r = idx % (CIN * K2);
    int k = r / CIN;
    int c = r % CIN;
    wt[idx] = f2bf(w[o * (CIN * K2) + c * K2 + k]);
}

__launch_bounds__(256)
__global__ void dcn_fb(const float* __restrict__ x, const float* __restrict__ off,
                       const unsigned short* __restrict__ wt, float* __restrict__ out) {
    __shared__ unsigned short s_s[64 * 66];
    const int tid = threadIdx.x;
    const int w = tid >> 6, l = tid & 63;
    const int bid = blockIdx.x;
    const int b = bid >> 8, t = bid & 255;
    const int ty0 = (t >> 4) << 3, tx0 = (t & 15) << 3;
    const int iy = l >> 3, ix = l & 7;
    const int ypix = ty0 + iy, xpix = tx0 + ix;
    f32x4 acc[4] = {{0,0,0,0},{0,0,0,0},{0,0,0,0},{0,0,0,0}};
    const int c0w = w * 16;
    for (int k = 0; k < K2; ++k) {
        float dy = off[(((b * (2*K2)) + 2*k    ) * HH + ypix) * WW + xpix];
        float dx = off[(((b * (2*K2)) + 2*k + 1) * HH + ypix) * WW + xpix];
        float py = dy + (float)(k / 3 + ypix - 1);
        float px = dx + (float)(k % 3 + xpix - 1);
        float fy = floorf(py), fx = floorf(px);
        float wy = py - fy, wx = px - fx;
        int y0 = (int)fy, x0 = (int)fx;
        int yc0 = min(max(y0, 0), HH-1), yc1 = min(max(y0+1, 0), HH-1);
        float ay0 = (y0 >= 0 && y0 <= HH-1) ? (1.f-wy) : 0.f;
        float ay1 = (y0 >= -1 && y0 <= HH-2) ? wy : 0.f;
        int xL = min(max(x0, 0), WW-2);
        float bx0 = (x0 >= 0 && x0 <= WW-1) ? (1.f-wx) : 0.f;
        float bx1 = (x0 >= -1 && x0 <= WW-2) ? wx : 0.f;
        bool sw = (x0 != xL);
        float wxa = sw ? bx1 : bx0, wxb = sw ? bx0 : bx1;
        float W0x = ay0*wxa, W0y = ay0*wxb, W1x = ay1*wxa, W1y = ay1*wxb;
        const float* r0 = x + ((b * CIN + c0w) * HH + yc0) * WW + xL;
        const float* r1 = x + ((b * CIN + c0w) * HH + yc1) * WW + xL;
        unsigned short* sd = &s_s[l * 66 + c0w];
        #pragma unroll
        for (int cc = 0; cc < 16; ++cc) {
            sd[cc] = f2bf(W0x*r0[0] + W0y*r0[1] + W1x*r1[0] + W1y*r1[1]);
            r0 += HH*WW; r1 += HH*WW;
        }
        __syncthreads();
        const int o_lane = l & 15, q = l >> 4;
        #pragma unroll
        for (int ks = 0; ks < 2; ++ks) {
            const int cb = ks*32 + q*8;
            const int row = w*16 + o_lane;
            const unsigned int* sp = (const unsigned int*)s_s;
            const int ib = row*33 + (cb >> 1);
            union { unsigned int u[4]; bf16x8 v; } af;
            af.u[0]=sp[ib]; af.u[1]=sp[ib+1]; af.u[2]=sp[ib+2]; af.u[3]=sp[ib+3];
            #pragma unroll
            for (int nt = 0; nt < 4; ++nt) {
                bf16x8 bfv = *(const bf16x8*)(wt + (nt*16 + o_lane) * (CIN*K2) + k*64 + cb);
                acc[nt] = __builtin_amdgcn_mfma_f32_16x16x32_bf16(af.v, bfv, acc[nt], 0, 0, 0);
            }
        }
        __syncthreads();
    }
    const int o_lane = l & 15, rq = (l >> 4) * 4;
    #pragma unroll
    for (int nt = 0; nt < 4; ++nt) {
        const int o = nt*16 + o_lane;
        #pragma unroll
        for (int j = 0; j < 4; ++j) {
            const int pix = w*16 + rq + j;
            out[(((size_t)b * COUT + o) * HH + ty0 + (pix>>3)) * WW + tx0 + (pix&7)] = acc[nt][j];
        }
    }
}

extern "C" void kernel_launch(void* const* d_in, const int* in_sizes, int n_in,
                              void* d_out, int out_size, void* d_ws, size_t ws_size,
                              hipStream_t stream) {
    const float* x   = (const float*)d_in[0];
    const float* off = (const float*)d_in[1];
    const float* wgt = (const float*)d_in[2];
    float* out = (float*)d_out;

    const size_t xt_bytes = (size_t)8 * HW * 64 * sizeof(unsigned short);     // 16 MiB
    const size_t wt_bytes = (size_t)COUT * CIN * K2 * sizeof(unsigned short); // 72 KiB

    if (ws_size >= xt_bytes + wt_bytes) {
        unsigned short* xt  = (unsigned short*)d_ws;
        unsigned short* wtp = (unsigned short*)((char*)d_ws + xt_bytes);
        xprep2_kernel<<<4096, 256, 0, stream>>>(x, xt);
        wprep_kernel<<<(COUT * CIN * K2 + 255) / 256, 256, 0, stream>>>(wgt, wtp);
        dcn_kernel<<<2048, 256, 0, stream>>>(xt, off, wtp, out);
    } else {
        unsigned short* wt = (unsigned short*)d_ws;
        wprep_fb<<<(COUT * CIN * K2 + 255) / 256, 256, 0, stream>>>(wgt, wt);
        dcn_fb<<<2048, 256, 0, stream>>>(x, off, wt, out);
    }
}

// Round 7
// 68.435 us; speedup vs baseline: 1.1279x; 1.1279x over previous
//
#include <hip/hip_runtime.h>
#include <hip/hip_bf16.h>

#define CIN  64
#define HH   128
#define WW   128
#define COUT 64
#define K2   9
#define HW   (HH * WW)

typedef __attribute__((ext_vector_type(8))) short bf16x8;
typedef __attribute__((ext_vector_type(4))) float f32x4;
typedef __attribute__((ext_vector_type(2))) float f32x2;
typedef __attribute__((ext_vector_type(4))) unsigned short u16x4;

__device__ __forceinline__ unsigned short f2bf(float f) {
    __hip_bfloat16 h = __float2bfloat16(f);
    return *reinterpret_cast<unsigned short*>(&h);
}
// unpack dword holding 2 bf16 (lo=ch j, hi=ch j+1) -> f32x2
__device__ __forceinline__ f32x2 up2(unsigned int d) {
    f32x2 r;
    r[0] = __uint_as_float(d << 16);
    r[1] = __uint_as_float(d & 0xffff0000u);
    return r;
}

// ---------------- prep: x fp32 NCHW -> bf16 slice-planes [b][s][y][x][8ch] ----------------
__launch_bounds__(256)
__global__ void xprep2_kernel(const float* __restrict__ x, unsigned short* __restrict__ xt) {
    const int idx = blockIdx.x * 256 + threadIdx.x;   // 2^20 total
    const int xw = idx & 127;
    const int y  = (idx >> 7) & 127;
    const int s  = (idx >> 14) & 7;
    const int b  = idx >> 17;
    const float* src = x + (((size_t)(b * CIN + s * 8) * HH) + y) * WW + xw;
    union { unsigned short us[8]; bf16x8 v; } u;
    #pragma unroll
    for (int j = 0; j < 8; ++j) u.us[j] = f2bf(src[(size_t)j * HW]);
    *(bf16x8*)(xt + ((((size_t)b * 8 + s) * HW) + y * WW + xw) * 8) = u.v;
}

// ---------------- prep: weight fp32 [o][c][k] -> bf16 MFMA-B-fragment order ----------------
// wtp[ ((k*2+ks)*4+nt)*64*8 + l*8 + j ] = W[o=nt*16+(l&15)][c=ks*32+(l>>4)*8+j][k]
__global__ void wprep_kernel(const float* __restrict__ w, unsigned short* __restrict__ wtp) {
    int idx = blockIdx.x * 256 + threadIdx.x;
    if (idx >= COUT * CIN * K2) return;
    int j  = idx & 7;
    int l  = (idx >> 3) & 63;
    int nt = (idx >> 9) & 3;
    int ks = (idx >> 11) & 1;
    int k  = idx >> 12;
    int o  = nt * 16 + (l & 15);
    int c  = ks * 32 + (l >> 4) * 8 + j;
    wtp[idx] = f2bf(w[(o * CIN + c) * K2 + k]);
}

// ---------------- main: tap-split 8-wave blocks, 16x4 tile, direct-fragment gather ----------
__launch_bounds__(512, 4)
__global__ void dcn_kernel(const unsigned short* __restrict__ xt,
                           const float* __restrict__ off,
                           const unsigned short* __restrict__ wtp,
                           float* __restrict__ out) {
    __shared__ float sred[64][66];              // merge buffer [tile-pixel][o], stride 66

    const int tid = threadIdx.x;
    const int w   = tid >> 6;                   // wave 0..7
    const int l   = tid & 63;
    const int wr  = w & 3;                      // pixel row within tile
    const int wh  = w >> 2;                     // tap half: 0 -> k=0..4, 1 -> k=5..8

    int bid = blockIdx.x;
    bid = (bid & 7) * 256 + (bid >> 3);         // XCD swizzle: one batch per XCD
    const int b   = bid >> 8;
    const int t   = bid & 255;
    const int ty0 = (t >> 3) << 2;              // 32 y-tiles of 4
    const int tx0 = (t & 7) << 4;               // 8  x-tiles of 16

    const int g      = l >> 4;                  // k-slice quad (A-frag minor index)
    const int lane16 = l & 15;                  // pixel x within row (A-frag row)

    f32x4 acc[4] = {{0,0,0,0},{0,0,0,0},{0,0,0,0},{0,0,0,0}};

    const float* offb = off + (size_t)b * (2 * K2) * HW;
    const unsigned short* xb  = xt + (size_t)b * HW * 64;
    const unsigned short* xp0 = xb + (size_t)g * HW * 8;        // plane for ks=0
    const unsigned short* xp1 = xb + (size_t)(g + 4) * HW * 8;  // plane for ks=1

    // this lane's pixel: row wr, x = lane16 (params AND fragment both belong to it)
    const int ypA  = ty0 + wr;
    const int xpA  = tx0 + lane16;
    const int offp = ypA * WW + xpA;

    // ---- pipeline state: all literal-indexed / named (spill-safe) ----
    f32x4 Pw[2];
    int   Pr0[2], Pr1[2];
    float oyv[2], oxv[2];
    bf16x8 G00L, G00R, G01L, G01R;
    bf16x8 G10L, G10R, G11L, G11R;
    bf16x8 bvv[2][4];
    bf16x8 af0, af1;

#define PARAMS(K, S) do {                                                     \
    const int kdy = (K) / 3 - 1, kdx = (K) % 3 - 1;                           \
    float py = oyv[S] + (float)(ypA + kdy);                                   \
    float px = oxv[S] + (float)(xpA + kdx);                                   \
    float fy = floorf(py), fx = floorf(px);                                   \
    float wy = py - fy, wxn = px - fx;                                        \
    int y0 = (int)fy, x0i = (int)fx;                                          \
    int yc0 = min(max(y0,     0), HH - 1);                                    \
    int yc1 = min(max(y0 + 1, 0), HH - 1);                                    \
    float ay0 = (y0 >= 0  && y0 <= HH - 1) ? (1.f - wy) : 0.f;                \
    float ay1 = (y0 >= -1 && y0 <= HH - 2) ? wy         : 0.f;                \
    int   xL  = min(max(x0i, 0), WW - 2);                                     \
    float bx0 = (x0i >= 0  && x0i <= WW - 1) ? (1.f - wxn) : 0.f;             \
    float bx1 = (x0i >= -1 && x0i <= WW - 2) ? wxn         : 0.f;             \
    bool  sw  = (x0i != xL);                                                  \
    float wxa = sw ? bx1 : bx0;                                               \
    float wxb = sw ? bx0 : bx1;                                               \
    Pw[S][0] = ay0 * wxa; Pw[S][1] = ay0 * wxb;                               \
    Pw[S][2] = ay1 * wxa; Pw[S][3] = ay1 * wxb;                               \
    Pr0[S] = (yc0 * WW + xL) * 8;                                             \
    Pr1[S] = (yc1 * WW + xL) * 8;                                             \
} while (0)

#define GATHER(S) do {                                                        \
    const unsigned short* r0p = xp0 + Pr0[S];                                 \
    const unsigned short* r1p = xp0 + Pr1[S];                                 \
    const unsigned short* r2p = xp1 + Pr0[S];                                 \
    const unsigned short* r3p = xp1 + Pr1[S];                                 \
    G00L = *(const bf16x8*)(r0p); G00R = *(const bf16x8*)(r0p + 8);           \
    G01L = *(const bf16x8*)(r1p); G01R = *(const bf16x8*)(r1p + 8);           \
    G10L = *(const bf16x8*)(r2p); G10R = *(const bf16x8*)(r2p + 8);           \
    G11L = *(const bf16x8*)(r3p); G11R = *(const bf16x8*)(r3p + 8);           \
} while (0)

#define IN1(S, GA, GB, GC, GD, AF) do {                                       \
    union { bf16x8 v; unsigned int d[4]; } ua, ub, uc, ud;                    \
    ua.v = GA; ub.v = GB; uc.v = GC; ud.v = GD;                               \
    union { unsigned short us[8]; bf16x8 v; } rr;                             \
    _Pragma("unroll")                                                         \
    for (int q = 0; q < 4; ++q) {                                             \
        f32x2 v = up2(ua.d[q]) * Pw[S][0] + up2(ub.d[q]) * Pw[S][1]           \
                + up2(uc.d[q]) * Pw[S][2] + up2(ud.d[q]) * Pw[S][3];          \
        rr.us[2*q]   = f2bf(v[0]);                                            \
        rr.us[2*q+1] = f2bf(v[1]);                                            \
    }                                                                         \
    AF = rr.v;                                                                \
} while (0)

#define INTERP(S) do {                                                        \
    IN1(S, G00L, G00R, G01L, G01R, af0);                                      \
    IN1(S, G10L, G10R, G11L, G11R, af1);                                      \
} while (0)

#define BVLOAD(K) do {                                                        \
    _Pragma("unroll")                                                         \
    for (int ks = 0; ks < 2; ++ks)                                            \
        _Pragma("unroll")                                                     \
        for (int nt = 0; nt < 4; ++nt)                                        \
            bvv[ks][nt] = *(const bf16x8*)(wtp + ((((K)*2 + ks)*4 + nt)*64 + l)*8); \
} while (0)

#define DOMFMA() do {                                                         \
    __builtin_amdgcn_s_setprio(1);                                            \
    _Pragma("unroll")                                                         \
    for (int nt = 0; nt < 4; ++nt)                                            \
        acc[nt] = __builtin_amdgcn_mfma_f32_16x16x32_bf16(af0, bvv[0][nt], acc[nt], 0, 0, 0); \
    _Pragma("unroll")                                                         \
    for (int nt = 0; nt < 4; ++nt)                                            \
        acc[nt] = __builtin_amdgcn_mfma_f32_16x16x32_bf16(af1, bvv[1][nt], acc[nt], 0, 0, 0); \
    __builtin_amdgcn_s_setprio(0);                                            \
} while (0)

#define STEP(K, CUR, NXT, KMAX) do {                                          \
    PARAMS((K) + 1, NXT);                                                     \
    if ((K) + 2 <= (KMAX)) {                                                  \
        oyv[CUR] = offb[(2 * ((K) + 2)    ) * HW + offp];                     \
        oxv[CUR] = offb[(2 * ((K) + 2) + 1) * HW + offp];                     \
    }                                                                         \
    BVLOAD(K);                                                                \
    INTERP(CUR);                                                              \
    GATHER(NXT);                                                              \
    DOMFMA();                                                                 \
} while (0)

    if (wh == 0) {
        // -------- taps 0..4 --------
        oyv[0] = offb[offp];          oxv[0] = offb[HW + offp];
        oyv[1] = offb[2 * HW + offp]; oxv[1] = offb[3 * HW + offp];
        PARAMS(0, 0);
        GATHER(0);
        STEP(0, 0, 1, 4); STEP(1, 1, 0, 4); STEP(2, 0, 1, 4); STEP(3, 1, 0, 4);
        BVLOAD(4); INTERP(0); DOMFMA();
    } else {
        // -------- taps 5..8 --------
        oyv[0] = offb[10 * HW + offp]; oxv[0] = offb[11 * HW + offp];
        oyv[1] = offb[12 * HW + offp]; oxv[1] = offb[13 * HW + offp];
        PARAMS(5, 0);
        GATHER(0);
        STEP(5, 0, 1, 8); STEP(6, 1, 0, 8); STEP(7, 0, 1, 8);
        BVLOAD(8); INTERP(1); DOMFMA();
    }

#undef PARAMS
#undef GATHER
#undef IN1
#undef INTERP
#undef BVLOAD
#undef DOMFMA
#undef STEP

    // -------- merge halves + store --------
    // C/D layout: col = l&15 (=o within nt), row = (l>>4)*4+j (= pixel x = rq+j)
    const int rq = g * 4;
    if (wh == 0) {
        #pragma unroll
        for (int nt = 0; nt < 4; ++nt)
            #pragma unroll
            for (int j = 0; j < 4; ++j)
                sred[wr * 16 + rq + j][nt * 16 + lane16] = acc[nt][j];
    }
    __syncthreads();
    if (wh == 1) {
        #pragma unroll
        for (int nt = 0; nt < 4; ++nt) {
            f32x4 v;
            #pragma unroll
            for (int j = 0; j < 4; ++j)
                v[j] = sred[wr * 16 + rq + j][nt * 16 + lane16] + acc[nt][j];
            const int o  = nt * 16 + lane16;
            const int yy = ty0 + wr;
            const int xx = tx0 + rq;
            *(f32x4*)&out[(((size_t)b * COUT + o) * HH + yy) * WW + xx] = v;
        }
    }
}

// ---------------- fallback path (no xt room): R0 kernel ----------------
__global__ void wprep_fb(const float* __restrict__ w, unsigned short* __restrict__ wt) {
    int idx = blockIdx.x * 256 + threadIdx.x;
    if (idx >= COUT * CIN * K2) return;
    int o = idx / (CIN * K2);
    int r = idx % (CIN * K2);
    int k = r / CIN;
    int c = r % CIN;
    wt[idx] = f2bf(w[o * (CIN * K2) + c * K2 + k]);
}

__launch_bounds__(256)
__global__ void dcn_fb(const float* __restrict__ x, const float* __restrict__ off,
                       const unsigned short* __restrict__ wt, float* __restrict__ out) {
    __shared__ unsigned short s_s[64 * 66];
    const int tid = threadIdx.x;
    const int w = tid >> 6, l = tid & 63;
    const int bid = blockIdx.x;
    const int b = bid >> 8, t = bid & 255;
    const int ty0 = (t >> 4) << 3, tx0 = (t & 15) << 3;
    const int iy = l >> 3, ix = l & 7;
    const int ypix = ty0 + iy, xpix = tx0 + ix;
    f32x4 acc[4] = {{0,0,0,0},{0,0,0,0},{0,0,0,0},{0,0,0,0}};
    const int c0w = w * 16;
    for (int k = 0; k < K2; ++k) {
        float dy = off[(((b * (2*K2)) + 2*k    ) * HH + ypix) * WW + xpix];
        float dx = off[(((b * (2*K2)) + 2*k + 1) * HH + ypix) * WW + xpix];
        float py = dy + (float)(k / 3 + ypix - 1);
        float px = dx + (float)(k % 3 + xpix - 1);
        float fy = floorf(py), fx = floorf(px);
        float wy = py - fy, wx = px - fx;
        int y0 = (int)fy, x0 = (int)fx;
        int yc0 = min(max(y0, 0), HH-1), yc1 = min(max(y0+1, 0), HH-1);
        float ay0 = (y0 >= 0 && y0 <= HH-1) ? (1.f-wy) : 0.f;
        float ay1 = (y0 >= -1 && y0 <= HH-2) ? wy : 0.f;
        int xL = min(max(x0, 0), WW-2);
        float bx0 = (x0 >= 0 && x0 <= WW-1) ? (1.f-wx) : 0.f;
        float bx1 = (x0 >= -1 && x0 <= WW-2) ? wx : 0.f;
        bool sw = (x0 != xL);
        float wxa = sw ? bx1 : bx0, wxb = sw ? bx0 : bx1;
        float W0x = ay0*wxa, W0y = ay0*wxb, W1x = ay1*wxa, W1y = ay1*wxb;
        const float* r0 = x + ((b * CIN + c0w) * HH + yc0) * WW + xL;
        const float* r1 = x + ((b * CIN + c0w) * HH + yc1) * WW + xL;
        unsigned short* sd = &s_s[l * 66 + c0w];
        #pragma unroll
        for (int cc = 0; cc < 16; ++cc) {
            sd[cc] = f2bf(W0x*r0[0] + W0y*r0[1] + W1x*r1[0] + W1y*r1[1]);
            r0 += HH*WW; r1 += HH*WW;
        }
        __syncthreads();
        const int o_lane = l & 15, q = l >> 4;
        #pragma unroll
        for (int ks = 0; ks < 2; ++ks) {
            const int cb = ks*32 + q*8;
            const int row = w*16 + o_lane;
            const unsigned int* sp = (const unsigned int*)s_s;
            const int ib = row*33 + (cb >> 1);
            union { unsigned int u[4]; bf16x8 v; } af;
            af.u[0]=sp[ib]; af.u[1]=sp[ib+1]; af.u[2]=sp[ib+2]; af.u[3]=sp[ib+3];
            #pragma unroll
            for (int nt = 0; nt < 4; ++nt) {
                bf16x8 bfv = *(const bf16x8*)(wt + (nt*16 + o_lane) * (CIN*K2) + k*64 + cb);
                acc[nt] = __builtin_amdgcn_mfma_f32_16x16x32_bf16(af.v, bfv, acc[nt], 0, 0, 0);
            }
        }
        __syncthreads();
    }
    const int o_lane = l & 15, rq = (l >> 4) * 4;
    #pragma unroll
    for (int nt = 0; nt < 4; ++nt) {
        const int o = nt*16 + o_lane;
        #pragma unroll
        for (int j = 0; j < 4; ++j) {
            const int pix = w*16 + rq + j;
            out[(((size_t)b * COUT + o) * HH + ty0 + (pix>>3)) * WW + tx0 + (pix&7)] = acc[nt][j];
        }
    }
}

extern "C" void kernel_launch(void* const* d_in, const int* in_sizes, int n_in,
                              void* d_out, int out_size, void* d_ws, size_t ws_size,
                              hipStream_t stream) {
    const float* x   = (const float*)d_in[0];
    const float* off = (const float*)d_in[1];
    const float* wgt = (const float*)d_in[2];
    float* out = (float*)d_out;

    const size_t xt_bytes = (size_t)8 * HW * 64 * sizeof(unsigned short);     // 16 MiB
    const size_t wt_bytes = (size_t)COUT * CIN * K2 * sizeof(unsigned short); // 72 KiB

    if (ws_size >= xt_bytes + wt_bytes) {
        unsigned short* xt  = (unsigned short*)d_ws;
        unsigned short* wtp = (unsigned short*)((char*)d_ws + xt_bytes);
        xprep2_kernel<<<4096, 256, 0, stream>>>(x, xt);
        wprep_kernel<<<(COUT * CIN * K2 + 255) / 256, 256, 0, stream>>>(wgt, wtp);
        dcn_kernel<<<2048, 512, 0, stream>>>(xt, off, wtp, out);
    } else {
        unsigned short* wt = (unsigned short*)d_ws;
        wprep_fb<<<(COUT * CIN * K2 + 255) / 256, 256, 0, stream>>>(wgt, wt);
        dcn_fb<<<2048, 256, 0, stream>>>(x, off, wt, out);
    }
}

// Round 8
// 62.196 us; speedup vs baseline: 1.2410x; 1.1003x over previous
//
#include <hip/hip_runtime.h>
#include <hip/hip_bf16.h>

#define CIN  64
#define HH   128
#define WW   128
#define COUT 64
#define K2   9
#define HW   (HH * WW)

typedef __attribute__((ext_vector_type(8))) short bf16x8;
typedef __attribute__((ext_vector_type(4))) float f32x4;
typedef __attribute__((ext_vector_type(2))) float f32x2;

__device__ __forceinline__ unsigned short f2bf(float f) {
    __hip_bfloat16 h = __float2bfloat16(f);
    return *reinterpret_cast<unsigned short*>(&h);
}
// unpack dword holding 2 bf16 (lo=ch j, hi=ch j+1) -> f32x2
__device__ __forceinline__ f32x2 up2(unsigned int d) {
    f32x2 r;
    r[0] = __uint_as_float(d << 16);
    r[1] = __uint_as_float(d & 0xffff0000u);
    return r;
}
// async global->LDS, 16B per lane; lds dest = base + lane*16 (wave-uniform base)
__device__ __forceinline__ void gl2lds16(const unsigned short* g, unsigned short* l) {
    __builtin_amdgcn_global_load_lds(
        (const __attribute__((address_space(1))) unsigned int*)g,
        (__attribute__((address_space(3))) unsigned int*)l, 16, 0, 0);
}

// ---------------- prep: x fp32 NCHW -> bf16 slice-planes [b][s][y][x][8ch] ----------------
__launch_bounds__(256)
__global__ void xprep2_kernel(const float* __restrict__ x, unsigned short* __restrict__ xt) {
    const int idx = blockIdx.x * 256 + threadIdx.x;   // 2^20 total
    const int xw = idx & 127;
    const int y  = (idx >> 7) & 127;
    const int s  = (idx >> 14) & 7;
    const int b  = idx >> 17;
    const float* src = x + (((size_t)(b * CIN + s * 8) * HH) + y) * WW + xw;
    union { unsigned short us[8]; bf16x8 v; } u;
    #pragma unroll
    for (int j = 0; j < 8; ++j) u.us[j] = f2bf(src[(size_t)j * HW]);
    *(bf16x8*)(xt + ((((size_t)b * 8 + s) * HW) + y * WW + xw) * 8) = u.v;
}

// ---------------- prep: weight fp32 [o][c][k] -> bf16 MFMA-B-fragment order ----------------
// wtp[ ((k*2+ks)*4+nt)*64*8 + l*8 + j ] = W[o=nt*16+(l&15)][c=ks*32+(l>>4)*8+j][k]
__global__ void wprep_kernel(const float* __restrict__ w, unsigned short* __restrict__ wtp) {
    int idx = blockIdx.x * 256 + threadIdx.x;
    if (idx >= COUT * CIN * K2) return;
    int j  = idx & 7;
    int l  = (idx >> 3) & 63;
    int nt = (idx >> 9) & 3;
    int ks = (idx >> 11) & 1;
    int k  = idx >> 12;
    int o  = nt * 16 + (l & 15);
    int c  = ks * 32 + (l >> 4) * 8 + j;
    wtp[idx] = f2bf(w[(o * CIN + c) * K2 + k]);
}

// ---------------- main: K-split 8-wave blocks, LDS-staged B, direct-fragment gather ---------
__launch_bounds__(512, 4)
__global__ void dcn_kernel(const unsigned short* __restrict__ xt,
                           const float* __restrict__ off,
                           const unsigned short* __restrict__ wtp,
                           float* __restrict__ out) {
    __shared__ unsigned short lsB[2][4096];     // double-buffered B tap (8 KB each)
    __shared__ float sred[64][66];              // merge buffer [tile-pixel][o]

    const int tid = threadIdx.x;
    const int w   = tid >> 6;                   // wave 0..7
    const int l   = tid & 63;
    const int wr  = w & 3;                      // pixel row within tile
    const int wh  = w >> 2;                     // K half: channels wh*32 .. wh*32+31

    int bid = blockIdx.x;
    bid = (bid & 7) * 256 + (bid >> 3);         // XCD swizzle: one batch per XCD
    const int b   = bid >> 8;
    const int t   = bid & 255;
    const int ty0 = (t >> 3) << 2;              // 32 y-tiles of 4
    const int tx0 = (t & 7) << 4;               // 8  x-tiles of 16

    const int g      = l >> 4;                  // k-slice quad within half
    const int lane16 = l & 15;                  // pixel x within row

    f32x4 acc[4] = {{0,0,0,0},{0,0,0,0},{0,0,0,0},{0,0,0,0}};

    const float* offb = off + (size_t)b * (2 * K2) * HW;
    // this wave's channel plane: channels (wh*4+g)*8 .. +8
    const unsigned short* xp = xt + ((size_t)b * 8 + (wh * 4 + g)) * HW * 8;

    // this lane's pixel
    const int ypA  = ty0 + wr;
    const int xpA  = tx0 + lane16;
    const int offp = ypA * WW + xpA;

    // ---- pipeline state: constant-indexed after full unroll (spill-safe) ----
    f32x4 Pw[2];
    int   Pr0[2], Pr1[2];
    float oyv[2], oxv[2];
    bf16x8 Gst[2][4];                           // double-buffered gather stage
    bf16x8 bvv[4];
    bf16x8 af;

#define PARAMS(K, S) do {                                                     \
    const int kdy = (K) / 3 - 1, kdx = (K) % 3 - 1;                           \
    float py = oyv[S] + (float)(ypA + kdy);                                   \
    float px = oxv[S] + (float)(xpA + kdx);                                   \
    float fy = floorf(py), fx = floorf(px);                                   \
    float wy = py - fy, wxn = px - fx;                                        \
    int y0 = (int)fy, x0i = (int)fx;                                          \
    int yc0 = min(max(y0,     0), HH - 1);                                    \
    int yc1 = min(max(y0 + 1, 0), HH - 1);                                    \
    float ay0 = (y0 >= 0  && y0 <= HH - 1) ? (1.f - wy) : 0.f;                \
    float ay1 = (y0 >= -1 && y0 <= HH - 2) ? wy         : 0.f;                \
    int   xL  = min(max(x0i, 0), WW - 2);                                     \
    float bx0 = (x0i >= 0  && x0i <= WW - 1) ? (1.f - wxn) : 0.f;             \
    float bx1 = (x0i >= -1 && x0i <= WW - 2) ? wxn         : 0.f;             \
    bool  sw  = (x0i != xL);                                                  \
    float wxa = sw ? bx1 : bx0;                                               \
    float wxb = sw ? bx0 : bx1;                                               \
    Pw[S][0] = ay0 * wxa; Pw[S][1] = ay0 * wxb;                               \
    Pw[S][2] = ay1 * wxa; Pw[S][3] = ay1 * wxb;                               \
    Pr0[S] = (yc0 * WW + xL) * 8;                                             \
    Pr1[S] = (yc1 * WW + xL) * 8;                                             \
} while (0)

#define GATHER(S) do {                                                        \
    const unsigned short* r0p = xp + Pr0[S];                                  \
    const unsigned short* r1p = xp + Pr1[S];                                  \
    Gst[S][0] = *(const bf16x8*)(r0p); Gst[S][1] = *(const bf16x8*)(r0p + 8); \
    Gst[S][2] = *(const bf16x8*)(r1p); Gst[S][3] = *(const bf16x8*)(r1p + 8); \
} while (0)

#define INTERP(S) do {                                                        \
    union { bf16x8 v; unsigned int d[4]; } ua, ub, uc, ud;                    \
    ua.v = Gst[S][0]; ub.v = Gst[S][1]; uc.v = Gst[S][2]; ud.v = Gst[S][3];   \
    union { unsigned short us[8]; bf16x8 v; } rr;                             \
    _Pragma("unroll")                                                         \
    for (int q = 0; q < 4; ++q) {                                             \
        f32x2 v = up2(ua.d[q]) * Pw[S][0] + up2(ub.d[q]) * Pw[S][1]           \
                + up2(uc.d[q]) * Pw[S][2] + up2(ud.d[q]) * Pw[S][3];          \
        rr.us[2*q]   = f2bf(v[0]);                                            \
        rr.us[2*q+1] = f2bf(v[1]);                                            \
    }                                                                         \
    af = rr.v;                                                                \
} while (0)

#define BVLOAD(P) do {                                                        \
    _Pragma("unroll")                                                         \
    for (int nt = 0; nt < 4; ++nt)                                            \
        bvv[nt] = *(const bf16x8*)(&lsB[P][(wh * 4 + nt) * 512 + l * 8]);     \
} while (0)

#define STAGE(P, K) do {                                                      \
    gl2lds16(wtp + (K) * 4096 + w * 512 + l * 8, &lsB[P][w * 512]);           \
} while (0)

#define DOMFMA() do {                                                         \
    __builtin_amdgcn_s_setprio(1);                                            \
    _Pragma("unroll")                                                         \
    for (int nt = 0; nt < 4; ++nt)                                            \
        acc[nt] = __builtin_amdgcn_mfma_f32_16x16x32_bf16(af, bvv[nt], acc[nt], 0, 0, 0); \
    __builtin_amdgcn_s_setprio(0);                                            \
} while (0)

    // -------- prologue: stage tap 0 B, gather tap 0, offsets for taps 0/1 --------
    STAGE(0, 0);
    oyv[0] = offb[offp];          oxv[0] = offb[HW + offp];
    oyv[1] = offb[2 * HW + offp]; oxv[1] = offb[3 * HW + offp];
    PARAMS(0, 0);
    GATHER(0);
    __syncthreads();                            // stage(0) + gathers(0) complete

    // -------- 9 lockstep tap-steps, fully unrolled --------
    #pragma unroll
    for (int s = 0; s < K2; ++s) {
        const int cur = s & 1, nxt = cur ^ 1;
        if (s < 8) {
            STAGE(nxt, s + 1);                  // B for next tap -> other LDS buf
            PARAMS(s + 1, nxt);
            if (s < 7) {
                oyv[cur] = offb[(2 * (s + 2)    ) * HW + offp];
                oxv[cur] = offb[(2 * (s + 2) + 1) * HW + offp];
            }
            GATHER(nxt);                        // in flight across BVLOAD+INTERP+MFMA
        }
        BVLOAD(cur);                            // ds_read current tap's B
        INTERP(cur);
        DOMFMA();
        if (s < 8) __syncthreads();             // fences stage/gather; WAR on lsB
    }

#undef PARAMS
#undef GATHER
#undef INTERP
#undef BVLOAD
#undef STAGE
#undef DOMFMA

    // -------- merge K-halves + store --------
    // C/D layout: col = l&15 (=o within nt), row = (l>>4)*4+j (= pixel x = g*4+j)
    const int rq = g * 4;
    if (wh == 0) {
        #pragma unroll
        for (int nt = 0; nt < 4; ++nt)
            #pragma unroll
            for (int j = 0; j < 4; ++j)
                sred[wr * 16 + rq + j][nt * 16 + lane16] = acc[nt][j];
    }
    __syncthreads();
    if (wh == 1) {
        #pragma unroll
        for (int nt = 0; nt < 4; ++nt) {
            f32x4 v;
            #pragma unroll
            for (int j = 0; j < 4; ++j)
                v[j] = sred[wr * 16 + rq + j][nt * 16 + lane16] + acc[nt][j];
            const int o  = nt * 16 + lane16;
            const int yy = ty0 + wr;
            const int xx = tx0 + rq;
            *(f32x4*)&out[(((size_t)b * COUT + o) * HH + yy) * WW + xx] = v;
        }
    }
}

// ---------------- fallback path (no xt room): R0 kernel ----------------
__global__ void wprep_fb(const float* __restrict__ w, unsigned short* __restrict__ wt) {
    int idx = blockIdx.x * 256 + threadIdx.x;
    if (idx >= COUT * CIN * K2) return;
    int o = idx / (CIN * K2);
    int r = idx % (CIN * K2);
    int k = r / CIN;
    int c = r % CIN;
    wt[idx] = f2bf(w[o * (CIN * K2) + c * K2 + k]);
}

__launch_bounds__(256)
__global__ void dcn_fb(const float* __restrict__ x, const float* __restrict__ off,
                       const unsigned short* __restrict__ wt, float* __restrict__ out) {
    __shared__ unsigned short s_s[64 * 66];
    const int tid = threadIdx.x;
    const int w = tid >> 6, l = tid & 63;
    const int bid = blockIdx.x;
    const int b = bid >> 8, t = bid & 255;
    const int ty0 = (t >> 4) << 3, tx0 = (t & 15) << 3;
    const int iy = l >> 3, ix = l & 7;
    const int ypix = ty0 + iy, xpix = tx0 + ix;
    f32x4 acc[4] = {{0,0,0,0},{0,0,0,0},{0,0,0,0},{0,0,0,0}};
    const int c0w = w * 16;
    for (int k = 0; k < K2; ++k) {
        float dy = off[(((b * (2*K2)) + 2*k    ) * HH + ypix) * WW + xpix];
        float dx = off[(((b * (2*K2)) + 2*k + 1) * HH + ypix) * WW + xpix];
        float py = dy + (float)(k / 3 + ypix - 1);
        float px = dx + (float)(k % 3 + xpix - 1);
        float fy = floorf(py), fx = floorf(px);
        float wy = py - fy, wx = px - fx;
        int y0 = (int)fy, x0 = (int)fx;
        int yc0 = min(max(y0, 0), HH-1), yc1 = min(max(y0+1, 0), HH-1);
        float ay0 = (y0 >= 0 && y0 <= HH-1) ? (1.f-wy) : 0.f;
        float ay1 = (y0 >= -1 && y0 <= HH-2) ? wy : 0.f;
        int xL = min(max(x0, 0), WW-2);
        float bx0 = (x0 >= 0 && x0 <= WW-1) ? (1.f-wx) : 0.f;
        float bx1 = (x0 >= -1 && x0 <= WW-2) ? wx : 0.f;
        bool sw = (x0 != xL);
        float wxa = sw ? bx1 : bx0, wxb = sw ? bx0 : bx1;
        float W0x = ay0*wxa, W0y = ay0*wxb, W1x = ay1*wxa, W1y = ay1*wxb;
        const float* r0 = x + ((b * CIN + c0w) * HH + yc0) * WW + xL;
        const float* r1 = x + ((b * CIN + c0w) * HH + yc1) * WW + xL;
        unsigned short* sd = &s_s[l * 66 + c0w];
        #pragma unroll
        for (int cc = 0; cc < 16; ++cc) {
            sd[cc] = f2bf(W0x*r0[0] + W0y*r0[1] + W1x*r1[0] + W1y*r1[1]);
            r0 += HH*WW; r1 += HH*WW;
        }
        __syncthreads();
        const int o_lane = l & 15, q = l >> 4;
        #pragma unroll
        for (int ks = 0; ks < 2; ++ks) {
            const int cb = ks*32 + q*8;
            const int row = w*16 + o_lane;
            const unsigned int* sp = (const unsigned int*)s_s;
            const int ib = row*33 + (cb >> 1);
            union { unsigned int u[4]; bf16x8 v; } af;
            af.u[0]=sp[ib]; af.u[1]=sp[ib+1]; af.u[2]=sp[ib+2]; af.u[3]=sp[ib+3];
            #pragma unroll
            for (int nt = 0; nt < 4; ++nt) {
                bf16x8 bfv = *(const bf16x8*)(wt + (nt*16 + o_lane) * (CIN*K2) + k*64 + cb);
                acc[nt] = __builtin_amdgcn_mfma_f32_16x16x32_bf16(af.v, bfv, acc[nt], 0, 0, 0);
            }
        }
        __syncthreads();
    }
    const int o_lane = l & 15, rq = (l >> 4) * 4;
    #pragma unroll
    for (int nt = 0; nt < 4; ++nt) {
        const int o = nt*16 + o_lane;
        #pragma unroll
        for (int j = 0; j < 4; ++j) {
            const int pix = w*16 + rq + j;
            out[(((size_t)b * COUT + o) * HH + ty0 + (pix>>3)) * WW + tx0 + (pix&7)] = acc[nt][j];
        }
    }
}

extern "C" void kernel_launch(void* const* d_in, const int* in_sizes, int n_in,
                              void* d_out, int out_size, void* d_ws, size_t ws_size,
                              hipStream_t stream) {
    const float* x   = (const float*)d_in[0];
    const float* off = (const float*)d_in[1];
    const float* wgt = (const float*)d_in[2];
    float* out = (float*)d_out;

    const size_t xt_bytes = (size_t)8 * HW * 64 * sizeof(unsigned short);     // 16 MiB
    const size_t wt_bytes = (size_t)COUT * CIN * K2 * sizeof(unsigned short); // 72 KiB

    if (ws_size >= xt_bytes + wt_bytes) {
        unsigned short* xt  = (unsigned short*)d_ws;
        unsigned short* wtp = (unsigned short*)((char*)d_ws + xt_bytes);
        xprep2_kernel<<<4096, 256, 0, stream>>>(x, xt);
        wprep_kernel<<<(COUT * CIN * K2 + 255) / 256, 256, 0, stream>>>(wgt, wtp);
        dcn_kernel<<<2048, 512, 0, stream>>>(xt, off, wtp, out);
    } else {
        unsigned short* wt = (unsigned short*)d_ws;
        wprep_fb<<<(COUT * CIN * K2 + 255) / 256, 256, 0, stream>>>(wgt, wt);
        dcn_fb<<<2048, 256, 0, stream>>>(x, off, wt, out);
    }
}